// Round 8
// baseline (709.026 us; speedup 1.0000x reference)
//
#include <hip/hip_runtime.h>

// Problem constants (fixed by reference)
#define BB 256      // batch
#define TT 1024     // time steps
#define HH 32       // hidden
#define SS 16       // superstep length (steps per barrier)
#define NBK (TT/SS) // 64 blocks of 16 steps
#define NSS (NBK+9) // 73 supersteps (pipeline depth 9 stages + drain)
#define NT 512      // 8 waves
#define PAD 36      // stream row pad (floats) -> 144B rows, 16B aligned
#define GPAD 98     // gi row pad (floats)

// Superstep n schedule (each stage = one wave; stage s handles 16-step block n-s;
// every buffer is [2]-parity by block number; all edges cross exactly 1 barrier):
//   wv7 : emb gather blk n        -> ebuf      (global, latency-first)
//   wv6 : y1 = relu(W1@e)  blk n-1 -> y1s      (t-in-lanes, batched)
//   wv7 : y2 = relu(W2@y1) blk n-2 -> y2s
//   wv7 : y3 = relu(W3@y2) blk n-3 -> y3s
//   wv3 : gi0 = Wih0@y3+b  blk n-4 -> gib[0]   (t-in-lanes, no readlanes)
//   wv0 : gh0+gates        blk n-5 -> h0s      (serial 16 steps, regs)
//   wv4 : gi1              blk n-6 -> gib[1]
//   wv1 : gh1+gates        blk n-7 -> h1s
//   wv5 : gi2              blk n-8 -> gib[2]
//   wv2 : gh2+gates        blk n-9 -> out (direct global store)
// SIMD pairing (wave i -> SIMD i&3): {gh0,gi1} {gh1,gi2} {gh2,y1} {gi0,wv7}.

__device__ __forceinline__ float fast_rcp(float x) { return __builtin_amdgcn_rcpf(x); }
__device__ __forceinline__ float sigm(float x)     { return fast_rcp(1.f + __expf(-x)); }
__device__ __forceinline__ float tanh_fast(float x){ float e = __expf(2.f * x); return 1.f - 2.f * fast_rcp(e + 1.f); }
__device__ __forceinline__ float rlane(float v, int k) {
    return __int_as_float(__builtin_amdgcn_readlane(__float_as_int(v), k));
}

__global__ __launch_bounds__(NT, 1) void rnn_fused(
    const int*   __restrict__ xidx,   // [B,T]
    const float* __restrict__ hid,    // [L,B,H]
    const float* __restrict__ emb,    // [38000,H]
    const float* __restrict__ W1, const float* __restrict__ b1,
    const float* __restrict__ W2, const float* __restrict__ b2,
    const float* __restrict__ W3, const float* __restrict__ b3,
    const float* __restrict__ Wih,    // [L,3H,H]
    const float* __restrict__ Whh,    // [L,3H,H]
    const float* __restrict__ bih,    // [L,3H]
    const float* __restrict__ bhh,    // [L,3H]
    float*       __restrict__ out)    // [B*T*H] ++ [L*B*H]
{
    const int b   = blockIdx.x;
    const int tid = threadIdx.x;
    const int wv  = tid >> 6;
    const int ln  = tid & 63;
    const int lo  = ln & 31;

    // 6 stream buffers (PAD rows) + 3 gi buffers (GPAD rows) = 65280 B <= 64KB
    __shared__ alignas(16) float ebuf[2][SS][PAD];
    __shared__ alignas(16) float y1s [2][SS][PAD];
    __shared__ alignas(16) float y2s [2][SS][PAD];
    __shared__ alignas(16) float y3s [2][SS][PAD];
    __shared__ alignas(16) float h0s [2][SS][PAD];
    __shared__ alignas(16) float h1s [2][SS][PAD];
    __shared__ alignas(16) float gib [3][2][SS][GPAD];

    // ---------------- per-role register setup ----------------
    float wA[32], wB[32];                 // gh: Whh rows (others unused)
    float biasA = 0.f, biasB = 0.f;
    float v_h = 0.f;
    float biasv[24];                      // gi: 24 bih biases
    float mb[16];                         // MLP: 16 biases for my o-rows

    const int q  = ln >> 4;               // gi: quarter (g-group)
    const int tg = ln & 15;               // gi/MLP: time-in-block lane
    const int hh = ln >> 5;               // MLP: o-half

    if (wv < 3) {                                      // gh waves
        const float4* pA = reinterpret_cast<const float4*>(Whh + (size_t)(wv * 96 + ln) * HH);
        const float4* pB = reinterpret_cast<const float4*>(Whh + (size_t)(wv * 96 + 64 + lo) * HH);
        #pragma unroll
        for (int i = 0; i < 8; ++i) {
            reinterpret_cast<float4*>(wA)[i] = pA[i];
            reinterpret_cast<float4*>(wB)[i] = pB[i];
        }
        biasA = bhh[wv * 96 + ln];
        biasB = bhh[wv * 96 + 64 + lo];
        if (ln < HH) v_h = hid[(size_t)(wv * BB + b) * HH + ln];
    } else if (wv < 6) {                               // gi waves: bias preload
        const int l = wv - 3;
        const float* bbase = bih + l * 96 + q * 24;
        #pragma unroll
        for (int j = 0; j < 6; ++j)
            *reinterpret_cast<float4*>(&biasv[4 * j]) = *reinterpret_cast<const float4*>(&bbase[4 * j]);
    } else if (wv == 6) {                              // y1 wave
        const float* bb = b1 + hh * 16;
        #pragma unroll
        for (int j = 0; j < 4; ++j)
            *reinterpret_cast<float4*>(&mb[4 * j]) = *reinterpret_cast<const float4*>(&bb[4 * j]);
    }
    // wv7 loads b2/b3 inline below (two bias sets).
    float mb3[16];
    if (wv == 7) {
        const float* bb2 = b2 + hh * 16;
        const float* bb3 = b3 + hh * 16;
        #pragma unroll
        for (int j = 0; j < 4; ++j) {
            *reinterpret_cast<float4*>(&mb[4 * j])  = *reinterpret_cast<const float4*>(&bb2[4 * j]);
            *reinterpret_cast<float4*>(&mb3[4 * j]) = *reinterpret_cast<const float4*>(&bb3[4 * j]);
        }
    }
    __syncthreads();

    float* const out_seq = out + (size_t)b * TT * HH;
    float* const out_hf  = out + (size_t)BB * TT * HH;

    for (int n = 0; n < NSS; ++n) {
        if (wv < 3) {
            // ================= gh wave, layer wv: 16 serial recurrence steps ====
            const int blk = n - 5 - 2 * wv;
            if (blk >= 0 && blk < NBK) {
                const int p = blk & 1;
                const float* gsrc = &gib[wv][p][0][0];
                __builtin_amdgcn_s_setprio(1);
                for (int t2 = 0; t2 < SS; ++t2) {
                    const float giA = gsrc[t2 * GPAD + ln];        // r/z rows
                    const float giB = gsrc[t2 * GPAD + 64 + lo];   // n rows
                    float a0 = biasA, a1 = 0.f, c0 = biasB, c1 = 0.f;
                    #pragma unroll
                    for (int k = 0; k < 32; k += 2) {
                        const float h0 = rlane(v_h, k), h1 = rlane(v_h, k + 1);
                        a0 = fmaf(wA[k],     h0, a0);
                        a1 = fmaf(wA[k + 1], h1, a1);
                        c0 = fmaf(wB[k],     h0, c0);
                        c1 = fmaf(wB[k + 1], h1, c1);
                    }
                    const float sA  = giA + a0 + a1;     // r-pre (lanes<32) / z-pre
                    const float ghB = c0 + c1;           // h_n (biased)
                    const float zp  = __shfl_xor(sA, 32);
                    const float r   = sigm(sA);
                    const float z   = sigm(zp);
                    const float nn  = tanh_fast(fmaf(r, ghB, giB));
                    const float hn  = fmaf(z, v_h - nn, nn);
                    v_h = hn;
                    if (ln < HH) {
                        if (wv == 0)      h0s[p][t2][ln] = hn;
                        else if (wv == 1) h1s[p][t2][ln] = hn;
                        else out_seq[(size_t)(blk * SS + t2) * HH + ln] = hn;
                    }
                }
                __builtin_amdgcn_s_setprio(0);
            }
        } else if (wv < 6) {
            // ================= gi wave, layer l: batched t-in-lanes =============
            const int l   = wv - 3;
            const int blk = n - 4 - 2 * l;
            if (blk >= 0 && blk < NBK) {
                const int p = blk & 1;
                const float* xsrc = (l == 0) ? &y3s[p][tg][0]
                                  : (l == 1) ? &h0s[p][tg][0]
                                             : &h1s[p][tg][0];
                float xv[32];
                #pragma unroll
                for (int j = 0; j < 8; ++j)
                    *reinterpret_cast<float4*>(&xv[4 * j]) = *reinterpret_cast<const float4*>(&xsrc[4 * j]);
                const float* wbase = Wih + ((size_t)l * 96 + q * 24) * HH;
                float* gdst = &gib[l][p][tg][q * 24];
                #pragma unroll 2
                for (int i = 0; i < 24; ++i) {
                    const float4* wr = reinterpret_cast<const float4*>(wbase + (size_t)i * HH);
                    float a0 = biasv[i], a1 = 0.f, a2 = 0.f, a3 = 0.f;
                    #pragma unroll
                    for (int j = 0; j < 8; ++j) {
                        const float4 w = wr[j];
                        a0 = fmaf(w.x, xv[4 * j + 0], a0);
                        a1 = fmaf(w.y, xv[4 * j + 1], a1);
                        a2 = fmaf(w.z, xv[4 * j + 2], a2);
                        a3 = fmaf(w.w, xv[4 * j + 3], a3);
                    }
                    gdst[i] = (a0 + a1) + (a2 + a3);
                }
            }
        } else if (wv == 6) {
            // ================= y1 wave: blk n-1, t-in-lanes (o-half per lane) ===
            const int blk = n - 1;
            if (blk >= 0 && blk < NBK) {
                const int p = blk & 1;
                float ev[32];
                #pragma unroll
                for (int j = 0; j < 8; ++j)
                    *reinterpret_cast<float4*>(&ev[4 * j]) = *reinterpret_cast<const float4*>(&ebuf[p][tg][4 * j]);
                float y1r[16];
                const float* w1b = W1 + (size_t)hh * 16 * HH;
                #pragma unroll 2
                for (int i = 0; i < 16; ++i) {
                    const float4* wr = reinterpret_cast<const float4*>(w1b + (size_t)i * HH);
                    float a0 = mb[i], a1 = 0.f, a2 = 0.f, a3 = 0.f;
                    #pragma unroll
                    for (int j = 0; j < 8; ++j) {
                        const float4 w = wr[j];
                        a0 = fmaf(w.x, ev[4 * j + 0], a0);
                        a1 = fmaf(w.y, ev[4 * j + 1], a1);
                        a2 = fmaf(w.z, ev[4 * j + 2], a2);
                        a3 = fmaf(w.w, ev[4 * j + 3], a3);
                    }
                    y1r[i] = fmaxf((a0 + a1) + (a2 + a3), 0.f);
                }
                #pragma unroll
                for (int j = 0; j < 4; ++j)
                    *reinterpret_cast<float4*>(&y1s[p][tg][hh * 16 + 4 * j]) =
                        *reinterpret_cast<float4*>(&y1r[4 * j]);
            }
        } else {
            // ================= wv7: emb gather (n) + y2 (n-2) + y3 (n-3) ========
            const int blk_e = n;
            if (blk_e < NBK) {                       // fire gather loads first
                const int pe = blk_e & 1, t0 = blk_e * SS;
                #pragma unroll
                for (int k = 0; k < 2; ++k) {
                    const int task = k * 64 + ln;    // 128 tasks: 16 rows x 8 chunks
                    const int row = task >> 3, qq = task & 7;
                    const int tok = xidx[b * TT + t0 + row];
                    const float4 v = *reinterpret_cast<const float4*>(emb + (size_t)tok * HH + qq * 4);
                    *reinterpret_cast<float4*>(&ebuf[pe][row][qq * 4]) = v;
                }
            }
            const int blk2 = n - 2;                  // y2 from y1s
            if (blk2 >= 0 && blk2 < NBK) {
                const int p = blk2 & 1;
                float x1[32];
                #pragma unroll
                for (int j = 0; j < 8; ++j)
                    *reinterpret_cast<float4*>(&x1[4 * j]) = *reinterpret_cast<const float4*>(&y1s[p][tg][4 * j]);
                float y2r[16];
                const float* w2b = W2 + (size_t)hh * 16 * HH;
                #pragma unroll 2
                for (int i = 0; i < 16; ++i) {
                    const float4* wr = reinterpret_cast<const float4*>(w2b + (size_t)i * HH);
                    float a0 = mb[i], a1 = 0.f, a2 = 0.f, a3 = 0.f;
                    #pragma unroll
                    for (int j = 0; j < 8; ++j) {
                        const float4 w = wr[j];
                        a0 = fmaf(w.x, x1[4 * j + 0], a0);
                        a1 = fmaf(w.y, x1[4 * j + 1], a1);
                        a2 = fmaf(w.z, x1[4 * j + 2], a2);
                        a3 = fmaf(w.w, x1[4 * j + 3], a3);
                    }
                    y2r[i] = fmaxf((a0 + a1) + (a2 + a3), 0.f);
                }
                #pragma unroll
                for (int j = 0; j < 4; ++j)
                    *reinterpret_cast<float4*>(&y2s[p][tg][hh * 16 + 4 * j]) =
                        *reinterpret_cast<float4*>(&y2r[4 * j]);
            }
            const int blk3 = n - 3;                  // y3 from y2s
            if (blk3 >= 0 && blk3 < NBK) {
                const int p = blk3 & 1;
                float x2[32];
                #pragma unroll
                for (int j = 0; j < 8; ++j)
                    *reinterpret_cast<float4*>(&x2[4 * j]) = *reinterpret_cast<const float4*>(&y2s[p][tg][4 * j]);
                float y3r[16];
                const float* w3b = W3 + (size_t)hh * 16 * HH;
                #pragma unroll 2
                for (int i = 0; i < 16; ++i) {
                    const float4* wr = reinterpret_cast<const float4*>(w3b + (size_t)i * HH);
                    float a0 = mb3[i], a1 = 0.f, a2 = 0.f, a3 = 0.f;
                    #pragma unroll
                    for (int j = 0; j < 8; ++j) {
                        const float4 w = wr[j];
                        a0 = fmaf(w.x, x2[4 * j + 0], a0);
                        a1 = fmaf(w.y, x2[4 * j + 1], a1);
                        a2 = fmaf(w.z, x2[4 * j + 2], a2);
                        a3 = fmaf(w.w, x2[4 * j + 3], a3);
                    }
                    y3r[i] = fmaxf((a0 + a1) + (a2 + a3), 0.f);
                }
                #pragma unroll
                for (int j = 0; j < 4; ++j)
                    *reinterpret_cast<float4*>(&y3s[p][tg][hh * 16 + 4 * j]) =
                        *reinterpret_cast<float4*>(&y3r[4 * j]);
            }
        }
        __syncthreads();   // one barrier per 16 steps
    }

    if (wv < 3 && ln < HH)
        out_hf[(size_t)(wv * BB + b) * HH + ln] = v_h;
}

extern "C" void kernel_launch(void* const* d_in, const int* in_sizes, int n_in,
                              void* d_out, int out_size, void* d_ws, size_t ws_size,
                              hipStream_t stream) {
    const int*   x   = (const int*)  d_in[0];
    const float* hid = (const float*)d_in[1];
    const float* emb = (const float*)d_in[2];
    const float* W1  = (const float*)d_in[3];
    const float* b1  = (const float*)d_in[4];
    const float* W2  = (const float*)d_in[5];
    const float* b2  = (const float*)d_in[6];
    const float* W3  = (const float*)d_in[7];
    const float* b3  = (const float*)d_in[8];
    const float* Wih = (const float*)d_in[9];
    const float* Whh = (const float*)d_in[10];
    const float* bih = (const float*)d_in[11];
    const float* bhh = (const float*)d_in[12];

    rnn_fused<<<dim3(BB), dim3(NT), 0, stream>>>(
        x, hid, emb, W1, b1, W2, b2, W3, b3, Wih, Whh, bih, bhh, (float*)d_out);
}